// Round 1
// baseline (1572.641 us; speedup 1.0000x reference)
//
#include <hip/hip_runtime.h>
#include <hip/hip_bf16.h>

// Causal scaled-dot-product attention, B=4 H=16 S=2048 D=64, fp32 in/out.
// Outputs: context [B,H,S,64] then attn [B,H,S,S], concatenated flat.
// Strategy: 1 WG (256 thr / 4 waves) per 16-query strip per (b,h).
// bf16 MFMA for QK^T and PV; full score strip (16 x 2048 bf16) in LDS.
// Memory floor is the 1.07 GB attn write -> design for coalesced stores.

#define S 2048
#define DK 64
#define BH 64               // B*H
#define NSTRIP 128          // S/16
#define SCS 2056            // LDS row stride in bf16 elems: 16B-aligned (4112 B)
#define CTX_ELEMS (BH * S * DK)   // 8388608

typedef __attribute__((ext_vector_type(8))) short bf16x8;
typedef __attribute__((ext_vector_type(4))) float f32x4;

__device__ __forceinline__ short f2bf(float f) {
    union { float f; unsigned u; } v; v.f = f;
    unsigned r = (v.u + 0x7FFFu + ((v.u >> 16) & 1u)) >> 16;
    return (short)r;
}
__device__ __forceinline__ float bf2f(short s) {
    union { unsigned u; float f; } v;
    v.u = ((unsigned)(unsigned short)s) << 16;
    return v.f;
}
__device__ __forceinline__ bf16x8 pack8(float4 x, float4 y) {
    bf16x8 r;
    r[0] = f2bf(x.x); r[1] = f2bf(x.y); r[2] = f2bf(x.z); r[3] = f2bf(x.w);
    r[4] = f2bf(y.x); r[5] = f2bf(y.y); r[6] = f2bf(y.z); r[7] = f2bf(y.w);
    return r;
}

__global__ __launch_bounds__(256, 2)
void sdpa_causal_kernel(const float* __restrict__ Q,
                        const float* __restrict__ K,
                        const float* __restrict__ V,
                        float* __restrict__ out) {
    __shared__ short sc[16 * SCS];      // scores then e=exp(s-m), bf16
    __shared__ float row_inv[16];       // 1/l per strip row

    const int qb = NSTRIP - 1 - blockIdx.x;   // big strips dispatch first
    const int bh = blockIdx.y;
    const int qs = qb * 16;
    const int ncols = (qb + 1) * 16;          // valid key columns (tile-aligned)

    const int tid = threadIdx.x;
    const int w = tid >> 6;          // wave 0..3
    const int lane = tid & 63;
    const int quad = lane >> 4;      // 0..3
    const int mrow = lane & 15;      // A-frag m / C-frag col index

    float* ctx  = out;
    float* attn = out + (size_t)CTX_ELEMS;

    // ---- zero-fill score LDS (covers K=32 pad tile + safety) ----
    {
        int4 z = {0, 0, 0, 0};
        int4* p = (int4*)sc;
        const int nchunks = (16 * SCS * 2) / 16;   // 4112
        for (int i = tid; i < nchunks; i += 256) p[i] = z;
    }
    __syncthreads();

    // ---- Phase 1: S = scale * Q K^T  (causal masked), bf16 into LDS ----
    // A-frag: Q[qs+mrow][kc*32 + quad*8 + j]   (m=lane&15, k=quad*8+j)
    // B-frag: K[nt*16+mrow][kc*32 + quad*8 + j] (n=lane&15, k=quad*8+j)
    // C-frag: row = quad*4+reg, col = lane&15
    {
        bf16x8 aQ[2];
        const float* Qrow = Q + ((size_t)(bh * S + qs + mrow)) * DK;
        #pragma unroll
        for (int kc = 0; kc < 2; ++kc) {
            float4 x = *(const float4*)(Qrow + kc * 32 + quad * 8);
            float4 y = *(const float4*)(Qrow + kc * 32 + quad * 8 + 4);
            aQ[kc] = pack8(x, y);
        }
        for (int nt = w; nt <= qb; nt += 4) {
            const float* Krow = K + ((size_t)(bh * S + nt * 16 + mrow)) * DK;
            f32x4 acc = {0.f, 0.f, 0.f, 0.f};
            #pragma unroll
            for (int kc = 0; kc < 2; ++kc) {
                float4 x = *(const float4*)(Krow + kc * 32 + quad * 8);
                float4 y = *(const float4*)(Krow + kc * 32 + quad * 8 + 4);
                bf16x8 bK = pack8(x, y);
                acc = __builtin_amdgcn_mfma_f32_16x16x32_bf16(aQ[kc], bK, acc, 0, 0, 0);
            }
            #pragma unroll
            for (int r = 0; r < 4; ++r) {
                int rloc = quad * 4 + r;           // strip row 0..15
                int gcol = nt * 16 + mrow;         // key column
                float val = acc[r] * 0.125f;
                if (gcol > qs + rloc) val = -INFINITY;   // causal mask
                sc[rloc * SCS + gcol] = f2bf(val);
            }
        }
    }
    __syncthreads();

    // ---- Phase 2: per-row softmax stats; overwrite s with e=exp(s-m) ----
    for (int r = 0; r < 4; ++r) {
        const int row = w * 4 + r;
        float mx = -INFINITY;
        for (int c = lane * 8; c < ncols; c += 512) {
            bf16x8 v = *(const bf16x8*)&sc[row * SCS + c];
            #pragma unroll
            for (int i = 0; i < 8; ++i) mx = fmaxf(mx, bf2f(v[i]));
        }
        #pragma unroll
        for (int off = 32; off; off >>= 1) mx = fmaxf(mx, __shfl_xor(mx, off));

        float sum = 0.f;
        for (int c = lane * 8; c < ncols; c += 512) {
            bf16x8 v = *(const bf16x8*)&sc[row * SCS + c];
            bf16x8 e;
            #pragma unroll
            for (int i = 0; i < 8; ++i) {
                float ev = __expf(bf2f(v[i]) - mx);
                sum += ev;
                e[i] = f2bf(ev);
            }
            *(bf16x8*)&sc[row * SCS + c] = e;
        }
        #pragma unroll
        for (int off = 32; off; off >>= 1) sum += __shfl_xor(sum, off);
        if (lane == 0) row_inv[row] = 1.0f / sum;
    }
    __syncthreads();

    // ---- Phase 3: write attn = e * (1/l)  + zeros for masked cols ----
    {
        float* attnBase = attn + (size_t)(bh * S + qs) * S;
        for (int row = 0; row < 16; ++row) {
            const float invl = row_inv[row];
            float* dst = attnBase + (size_t)row * S;
            const short* src = &sc[row * SCS];
            for (int c = tid * 4; c < ncols; c += 1024) {
                float4 o;
                o.x = bf2f(src[c + 0]) * invl;
                o.y = bf2f(src[c + 1]) * invl;
                o.z = bf2f(src[c + 2]) * invl;
                o.w = bf2f(src[c + 3]) * invl;
                *(float4*)(dst + c) = o;
            }
            float4 z = {0.f, 0.f, 0.f, 0.f};
            for (int c = ncols + tid * 4; c < S; c += 1024)
                *(float4*)(dst + c) = z;
        }
    }

    // ---- Phase 4: O = (e . V) * (1/l) via MFMA, j-chunks split over waves ----
    f32x4 o0 = {0.f,0.f,0.f,0.f}, o1 = o0, o2 = o0, o3 = o0;
    {
        const int NC32 = (ncols + 31) >> 5;
        for (int c = w; c < NC32; c += 4) {
            const int j0 = c * 32;
            // A-frag: e[mrow][j0 + quad*8 + j]  (contiguous 16B in LDS)
            bf16x8 aP = *(const bf16x8*)&sc[mrow * SCS + j0 + quad * 8];
            // B-frags: V[j0+quad*8+jj][dt*16 + mrow]  (column reads)
            #pragma unroll
            for (int dt = 0; dt < 4; ++dt) {
                const float* Vp = V + ((size_t)(bh * S + j0 + quad * 8)) * DK + dt * 16 + mrow;
                bf16x8 bV;
                #pragma unroll
                for (int jj = 0; jj < 8; ++jj) bV[jj] = f2bf(Vp[jj * DK]);
                f32x4 acc = dt == 0 ? o0 : dt == 1 ? o1 : dt == 2 ? o2 : o3;
                acc = __builtin_amdgcn_mfma_f32_16x16x32_bf16(aP, bV, acc, 0, 0, 0);
                if      (dt == 0) o0 = acc;
                else if (dt == 1) o1 = acc;
                else if (dt == 2) o2 = acc;
                else              o3 = acc;
            }
        }
    }
    __syncthreads();   // sc (e-values) dead after this point

    // ---- cross-wave O reduction through LDS (overlay on sc) ----
    {
        float* op = (float*)sc;   // [4 waves][16 rows][64 d] = 16 KB
        #pragma unroll
        for (int dt = 0; dt < 4; ++dt) {
            f32x4 acc = dt == 0 ? o0 : dt == 1 ? o1 : dt == 2 ? o2 : o3;
            #pragma unroll
            for (int r = 0; r < 4; ++r)
                op[(w * 16 + quad * 4 + r) * 64 + dt * 16 + mrow] = acc[r];
        }
        __syncthreads();
        #pragma unroll
        for (int k = 0; k < 4; ++k) {
            int idx = tid + k * 256;         // 0..1023
            int row = idx >> 6, d = idx & 63;
            float s = op[row * 64 + d] + op[(16 + row) * 64 + d]
                    + op[(32 + row) * 64 + d] + op[(48 + row) * 64 + d];
            ctx[((size_t)(bh * S + qs + row)) * DK + d] = s * row_inv[row];
        }
    }
}

extern "C" void kernel_launch(void* const* d_in, const int* in_sizes, int n_in,
                              void* d_out, int out_size, void* d_ws, size_t ws_size,
                              hipStream_t stream) {
    const float* Q = (const float*)d_in[0];
    const float* K = (const float*)d_in[1];
    const float* V = (const float*)d_in[2];
    // d_in[3] = attn_mask (causal, known statically) - unused
    float* out = (float*)d_out;
    dim3 grid(NSTRIP, BH);
    sdpa_causal_kernel<<<grid, 256, 0, stream>>>(Q, K, V, out);
}